// Round 1
// baseline (175.149 us; speedup 1.0000x reference)
//
#include <hip/hip_runtime.h>
#include <hip/hip_bf16.h>
#include <math.h>

// MultiEmbeddingSGNS: out[b] = sigmoid( dot( sum_i wt_i*T_i[x[b,i]],
//                                            sum_i wc_i*C_i[x[b,i]] ) )
// wt = softmax(tgt_w), wc = softmax(ctx_w), D=128, BS=16384.
//
// One wave (64 lanes) per batch element; lane l covers dims {2l, 2l+1} via
// float2 loads (512 B per row per vector instruction, fully coalesced).

#define D 128
#define WAVES_PER_BLOCK 4

__global__ __launch_bounds__(64 * WAVES_PER_BLOCK)
void sgns_kernel(const int* __restrict__ x,
                 const float* __restrict__ tgt_base,
                 const float* __restrict__ tgt_a,
                 const float* __restrict__ tgt_b,
                 const float* __restrict__ ctx_base,
                 const float* __restrict__ ctx_a,
                 const float* __restrict__ ctx_b,
                 const float* __restrict__ tgt_w,
                 const float* __restrict__ ctx_w,
                 float* __restrict__ out,
                 int bs) {
    const int wave = threadIdx.x >> 6;
    const int lane = threadIdx.x & 63;
    const int b = blockIdx.x * WAVES_PER_BLOCK + wave;
    if (b >= bs) return;

    // softmax(tgt_w), softmax(ctx_w) — 3 elements each, computed per-thread
    float t0 = tgt_w[0], t1 = tgt_w[1], t2 = tgt_w[2];
    float tm = fmaxf(t0, fmaxf(t1, t2));
    float te0 = __expf(t0 - tm), te1 = __expf(t1 - tm), te2 = __expf(t2 - tm);
    float tinv = 1.0f / (te0 + te1 + te2);
    float wt0 = te0 * tinv, wt1 = te1 * tinv, wt2 = te2 * tinv;

    float c0 = ctx_w[0], c1 = ctx_w[1], c2 = ctx_w[2];
    float cm = fmaxf(c0, fmaxf(c1, c2));
    float ce0 = __expf(c0 - cm), ce1 = __expf(c1 - cm), ce2 = __expf(c2 - cm);
    float cinv = 1.0f / (ce0 + ce1 + ce2);
    float wc0 = ce0 * cinv, wc1 = ce1 * cinv, wc2 = ce2 * cinv;

    const int i0 = x[b * 3 + 0];
    const int i1 = x[b * 3 + 1];
    const int i2 = x[b * 3 + 2];

    // float2 per lane: 64 lanes * 8 B = 512 B = one full D=128 row
    const float2* tb0 = (const float2*)(tgt_base + (size_t)i0 * D);
    const float2* tb1 = (const float2*)(tgt_a    + (size_t)i1 * D);
    const float2* tb2 = (const float2*)(tgt_b    + (size_t)i2 * D);
    const float2* cb0 = (const float2*)(ctx_base + (size_t)i0 * D);
    const float2* cb1 = (const float2*)(ctx_a    + (size_t)i1 * D);
    const float2* cb2 = (const float2*)(ctx_b    + (size_t)i2 * D);

    float2 ta = tb0[lane];
    float2 tbv = tb1[lane];
    float2 tc = tb2[lane];
    float2 ca = cb0[lane];
    float2 cbv = cb1[lane];
    float2 cc = cb2[lane];

    float tx = wt0 * ta.x + wt1 * tbv.x + wt2 * tc.x;
    float ty = wt0 * ta.y + wt1 * tbv.y + wt2 * tc.y;
    float cx = wc0 * ca.x + wc1 * cbv.x + wc2 * cc.x;
    float cy = wc0 * ca.y + wc1 * cbv.y + wc2 * cc.y;

    float p = tx * cx + ty * cy;

    // 64-lane wave reduction
    #pragma unroll
    for (int off = 32; off > 0; off >>= 1)
        p += __shfl_down(p, off, 64);

    if (lane == 0)
        out[b] = 1.0f / (1.0f + __expf(-p));
}

extern "C" void kernel_launch(void* const* d_in, const int* in_sizes, int n_in,
                              void* d_out, int out_size, void* d_ws, size_t ws_size,
                              hipStream_t stream) {
    const int*   x        = (const int*)  d_in[0];
    const float* tgt_base = (const float*)d_in[1];
    const float* tgt_a    = (const float*)d_in[2];
    const float* tgt_b    = (const float*)d_in[3];
    const float* ctx_base = (const float*)d_in[4];
    const float* ctx_a    = (const float*)d_in[5];
    const float* ctx_b    = (const float*)d_in[6];
    const float* tgt_w    = (const float*)d_in[7];
    const float* ctx_w    = (const float*)d_in[8];
    float* out = (float*)d_out;

    const int bs = out_size;  // 16384
    const int block = 64 * WAVES_PER_BLOCK;
    const int grid = (bs + WAVES_PER_BLOCK - 1) / WAVES_PER_BLOCK;

    sgns_kernel<<<grid, block, 0, stream>>>(x, tgt_base, tgt_a, tgt_b,
                                            ctx_base, ctx_a, ctx_b,
                                            tgt_w, ctx_w, out, bs);
}